// Round 1
// baseline (757.352 us; speedup 1.0000x reference)
//
#include <hip/hip_runtime.h>
#include <math.h>

// Problem constants
#define Bn 32
#define Sn 2048
#define Hn 512
#define En 512
#define Mn (Bn*Sn)   // 65536 rows of the flattened [B*S, H] matrices

using short8  = __attribute__((ext_vector_type(8))) short;   // 8 bf16 (4 VGPRs) MFMA A/B frag
using short4v = __attribute__((ext_vector_type(4))) short;
using floatx4 = __attribute__((ext_vector_type(4))) float;   // MFMA C/D frag

__device__ __forceinline__ unsigned short f2bf(float x) {
    unsigned u = __float_as_uint(x);
    u += 0x7FFFu + ((u >> 16) & 1u);   // round-to-nearest-even
    return (unsigned short)(u >> 16);
}

// ---------------------------------------------------------------------------
// K1: w[row] = exp(dot(alpha[row,:], Wa) + ba)   one wave per row
// ---------------------------------------------------------------------------
__global__ __launch_bounds__(256) void k_w(const float* __restrict__ alpha,
                                           const float* __restrict__ Wa,
                                           const float* __restrict__ ba,
                                           float* __restrict__ wout) {
    const int lane = threadIdx.x & 63;
    const int wq   = threadIdx.x >> 6;
    const int row  = blockIdx.x * 4 + wq;
    const float* ap = alpha + (size_t)row * Hn + lane * 8;
    const float* wp = Wa + lane * 8;
    float4 a0 = *(const float4*)ap;
    float4 a1 = *(const float4*)(ap + 4);
    float4 w0 = *(const float4*)wp;
    float4 w1 = *(const float4*)(wp + 4);
    float s = a0.x*w0.x + a0.y*w0.y + a0.z*w0.z + a0.w*w0.w
            + a1.x*w1.x + a1.y*w1.y + a1.z*w1.z + a1.w*w1.w;
    #pragma unroll
    for (int off = 32; off; off >>= 1) s += __shfl_down(s, off, 64);
    if (lane == 0) wout[row] = expf(s + ba[0]);
}

// ---------------------------------------------------------------------------
// K2: cw[b,:] = inclusive cumsum_s(w[b,:])   one wave per b (tiny)
// ---------------------------------------------------------------------------
__global__ __launch_bounds__(64) void k_scan_w(const float* __restrict__ w,
                                               float* __restrict__ cw) {
    const int b = blockIdx.x;
    const int lane = threadIdx.x;
    const float* wp = w  + (size_t)b * Sn;
    float*       cp = cw + (size_t)b * Sn;
    float carry = 0.f;
    for (int c = 0; c < Sn; c += 64) {
        float v = wp[c + lane];
        #pragma unroll
        for (int off = 1; off < 64; off <<= 1) {
            float t = __shfl_up(v, off, 64);
            if (lane >= off) v += t;
        }
        float o = carry + v;
        cp[c + lane] = o;
        carry = __shfl(o, 63, 64);
    }
}

// ---------------------------------------------------------------------------
// K3: t[r,e] = w[r] * tanh(beta[r,:]·Wb[e,:] + bb[e]) * embed[r,e]  -> d_out
//     bf16 MFMA GEMM, 64x64 block tile, convert fp32->bf16 during staging.
//     A = beta [M][K], B = Wb [N][K]  (A·B^T shape, both K-contiguous).
// ---------------------------------------------------------------------------
#define BKt 64
#define LDT 72   // 64 + 8 bf16 pad: keeps 16B alignment for ds_read_b128
__global__ __launch_bounds__(256) void k_gemm(const float* __restrict__ Aq,
                                              const float* __restrict__ Wb,
                                              const float* __restrict__ bb,
                                              const float* __restrict__ wv,
                                              const float* __restrict__ embed,
                                              float* __restrict__ outp) {
    __shared__ short lds_a[64 * LDT];
    __shared__ short lds_b[64 * LDT];
    const int tid    = threadIdx.x;
    const int blockN = blockIdx.x * 64;   // n fastest: 8 n-blocks share A panel in L3
    const int blockM = blockIdx.y * 64;
    const int srow = tid >> 4;            // 16 rows per staging pass
    const int scol = (tid & 15) << 2;     // float4 column
    const int lane = tid & 63, wq = tid >> 6;
    const int lrow = lane & 15;
    const int lk   = (lane >> 4) << 3;    // quad * 8

    floatx4 zero = {0.f, 0.f, 0.f, 0.f};
    floatx4 acc[4] = {zero, zero, zero, zero};

    for (int k0 = 0; k0 < Hn; k0 += BKt) {
        #pragma unroll
        for (int p = 0; p < 4; p++) {
            const int row = p * 16 + srow;
            float4 av = *(const float4*)(Aq + (size_t)(blockM + row) * Hn + k0 + scol);
            short4v sa; sa.x = f2bf(av.x); sa.y = f2bf(av.y); sa.z = f2bf(av.z); sa.w = f2bf(av.w);
            *(short4v*)&lds_a[row * LDT + scol] = sa;
            float4 bv = *(const float4*)(Wb + (size_t)(blockN + row) * Hn + k0 + scol);
            short4v sb; sb.x = f2bf(bv.x); sb.y = f2bf(bv.y); sb.z = f2bf(bv.z); sb.w = f2bf(bv.w);
            *(short4v*)&lds_b[row * LDT + scol] = sb;
        }
        __syncthreads();
        #pragma unroll
        for (int kk = 0; kk < BKt; kk += 32) {
            short8 bf = *(const short8*)&lds_b[(wq * 16 + lrow) * LDT + kk + lk];
            #pragma unroll
            for (int i = 0; i < 4; i++) {
                short8 af = *(const short8*)&lds_a[(i * 16 + lrow) * LDT + kk + lk];
                acc[i] = __builtin_amdgcn_mfma_f32_16x16x32_bf16(af, bf, acc[i], 0, 0, 0);
            }
        }
        __syncthreads();
    }

    // Epilogue: C/D layout col=lane&15, row=quad*4+reg  [m89-verified]
    const int ocol = blockN + wq * 16 + lrow;
    const float bbv = bb[ocol];
    const int r0 = blockM + ((lane >> 4) << 2);
    #pragma unroll
    for (int i = 0; i < 4; i++) {
        #pragma unroll
        for (int reg = 0; reg < 4; reg++) {
            const int r = r0 + i * 16 + reg;
            const float logit = acc[i][reg] + bbv;
            const float bwv = tanhf(logit);
            const size_t idx = (size_t)r * En + ocol;
            outp[idx] = wv[r] * bwv * embed[idx];
        }
    }
}

// ---------------------------------------------------------------------------
// K4: out[b,s,e] = cumsum_s(t[b,s,e]) / (cw[b,s] + 1e-10)   in-place in d_out
//     one thread per (b,e) column; e-lanes coalesced.
// ---------------------------------------------------------------------------
__global__ __launch_bounds__(256) void k_cumdiv(float* __restrict__ t,
                                                const float* __restrict__ cw) {
    const int col = blockIdx.x * 256 + threadIdx.x;
    const int b = col >> 9;
    const int e = col & 511;
    const float* cwp = cw + (size_t)b * Sn;
    float* p = t + (size_t)b * Sn * En + e;
    float acc = 0.f;
    for (int s = 0; s < Sn; s += 8) {
        float v[8], d[8];
        #pragma unroll
        for (int j = 0; j < 8; j++) v[j] = p[(size_t)(s + j) * En];
        #pragma unroll
        for (int j = 0; j < 8; j++) d[j] = cwp[s + j];
        #pragma unroll
        for (int j = 0; j < 8; j++) {
            acc += v[j];
            p[(size_t)(s + j) * En] = acc / (d[j] + 1e-10f);
        }
    }
}

extern "C" void kernel_launch(void* const* d_in, const int* in_sizes, int n_in,
                              void* d_out, int out_size, void* d_ws, size_t ws_size,
                              hipStream_t stream) {
    const float* alpha = (const float*)d_in[0];
    const float* beta  = (const float*)d_in[1];
    const float* embed = (const float*)d_in[2];
    const float* Wb    = (const float*)d_in[3];
    const float* bb    = (const float*)d_in[4];
    const float* Wa    = (const float*)d_in[5];
    const float* ba    = (const float*)d_in[6];
    float* out = (float*)d_out;

    float* wbuf  = (float*)d_ws;        // [Mn] w values
    float* cwbuf = wbuf + Mn;           // [Mn] cumsum of w

    k_w<<<Mn / 4, 256, 0, stream>>>(alpha, Wa, ba, wbuf);
    k_scan_w<<<Bn, 64, 0, stream>>>(wbuf, cwbuf);
    dim3 g3(En / 64, Mn / 64);
    k_gemm<<<g3, 256, 0, stream>>>(beta, Wb, bb, wbuf, embed, out);
    k_cumdiv<<<(Bn * En) / 256, 256, 0, stream>>>(out, cwbuf);
}

// Round 2
// 570.998 us; speedup vs baseline: 1.3264x; 1.3264x over previous
//
#include <hip/hip_runtime.h>
#include <math.h>

// Problem constants
#define Bn 32
#define Sn 2048
#define Hn 512
#define En 512
#define Mn (Bn*Sn)     // 65536 flattened [B*S] rows
#define CH 128         // s-rows per GEMM m-block == cumsum chunk size
#define NCH (Sn/CH)    // 16 chunks per batch
#define BK 64          // GEMM K-tile

using short8  = __attribute__((ext_vector_type(8))) short;   // 8 bf16 MFMA A/B frag
using floatx4 = __attribute__((ext_vector_type(4))) float;   // MFMA C/D frag

__device__ __forceinline__ unsigned short f2bf(float x) {
    unsigned u = __float_as_uint(x);
    u += 0x7FFFu + ((u >> 16) & 1u);   // RNE
    return (unsigned short)(u >> 16);
}

__device__ __forceinline__ float fast_tanh(float x) {
    x = fminf(20.f, fmaxf(-20.f, x));
    float e = __expf(2.f * x);
    return (e - 1.f) * __builtin_amdgcn_rcpf(e + 1.f);
}

// async 16B/lane global->LDS: LDS dest is wave-uniform base + lane*16 (m104/m108)
__device__ __forceinline__ void load_lds16(const unsigned short* g, unsigned short* l) {
    __builtin_amdgcn_global_load_lds((const __attribute__((address_space(1))) void*)g,
                                     (__attribute__((address_space(3))) void*)l,
                                     16, 0, 0);
}

// ---------------------------------------------------------------------------
// K0: fp32 -> bf16 bulk convert (beta, Wb). 8 elems/thread, BW-bound.
// ---------------------------------------------------------------------------
__global__ __launch_bounds__(256) void k_conv(const float* __restrict__ in,
                                              unsigned short* __restrict__ out, int n8) {
    int i = blockIdx.x * 256 + threadIdx.x;
    if (i >= n8) return;
    const float4 a = ((const float4*)in)[2*i];
    const float4 b = ((const float4*)in)[2*i + 1];
    short8 o;
    o[0]=f2bf(a.x); o[1]=f2bf(a.y); o[2]=f2bf(a.z); o[3]=f2bf(a.w);
    o[4]=f2bf(b.x); o[5]=f2bf(b.y); o[6]=f2bf(b.z); o[7]=f2bf(b.w);
    ((short8*)out)[i] = o;
}

// ---------------------------------------------------------------------------
// K1: w[row] = exp(dot(alpha[row,:], Wa) + ba)   one wave per row
// ---------------------------------------------------------------------------
__global__ __launch_bounds__(256) void k_w(const float* __restrict__ alpha,
                                           const float* __restrict__ Wa,
                                           const float* __restrict__ ba,
                                           float* __restrict__ wout) {
    const int lane = threadIdx.x & 63;
    const int wq   = threadIdx.x >> 6;
    const int row  = blockIdx.x * 4 + wq;
    const float* ap = alpha + (size_t)row * Hn + lane * 8;
    const float* wp = Wa + lane * 8;
    float4 a0 = *(const float4*)ap;
    float4 a1 = *(const float4*)(ap + 4);
    float4 w0 = *(const float4*)wp;
    float4 w1 = *(const float4*)(wp + 4);
    float s = a0.x*w0.x + a0.y*w0.y + a0.z*w0.z + a0.w*w0.w
            + a1.x*w1.x + a1.y*w1.y + a1.z*w1.z + a1.w*w1.w;
    #pragma unroll
    for (int off = 32; off; off >>= 1) s += __shfl_down(s, off, 64);
    if (lane == 0) wout[row] = expf(s + ba[0]);
}

// ---------------------------------------------------------------------------
// K2: cw[b,:] = inclusive cumsum_s(w[b,:])   one wave per b (tiny)
// ---------------------------------------------------------------------------
__global__ __launch_bounds__(64) void k_scan_w(const float* __restrict__ w,
                                               float* __restrict__ cw) {
    const int b = blockIdx.x;
    const int lane = threadIdx.x;
    const float* wp = w  + (size_t)b * Sn;
    float*       cp = cw + (size_t)b * Sn;
    float carry = 0.f;
    for (int c = 0; c < Sn; c += 64) {
        float v = wp[c + lane];
        #pragma unroll
        for (int off = 1; off < 64; off <<= 1) {
            float t = __shfl_up(v, off, 64);
            if (lane >= off) v += t;
        }
        float o = carry + v;
        cp[c + lane] = o;
        carry = __shfl(o, 63, 64);
    }
}

// ---------------------------------------------------------------------------
// K3: t[r,e] = w[r]*tanh(beta[r,:]·Wb[e,:]+bb[e])*embed[r,e] -> d_out
//     m97-style: 128x128 tile, BK=64, global_load_lds 16B staging from bf16.
//     Epilogue also writes per-(m-block) column sums -> partial[b][chunk][e].
//     m-block == one (b, s-chunk of 128): blocks never straddle batches.
// ---------------------------------------------------------------------------
__global__ __launch_bounds__(256) void k_gemm2(const unsigned short* __restrict__ Abf,
                                               const unsigned short* __restrict__ Bbf,
                                               const float* __restrict__ bbias,
                                               const float* __restrict__ wv,
                                               const float* __restrict__ embed,
                                               float* __restrict__ outp,
                                               float* __restrict__ partial) {
    __shared__ unsigned short lds_a[128 * BK];   // 16 KB, UNPADDED (global_load_lds order)
    __shared__ unsigned short lds_b[128 * BK];   // 16 KB
    const int tid  = threadIdx.x;
    const int lane = tid & 63, wq = tid >> 6;
    const int wave_n = wq & 1, wave_m = wq >> 1;   // 2x2 wave grid, 64x64 per wave
    const int blockN = blockIdx.x * 128;           // n fastest for A-panel locality
    const int blockM = blockIdx.y * 128;
    const int lrow = lane & 15;
    const int quad = lane >> 4;
    const int srow = wq * 32 + (lane >> 3);        // staging: 8 rows per instr
    const int scol = (lane & 7) * 8;               // bf16 col within K-tile

    floatx4 acc[4][4];
    #pragma unroll
    for (int i = 0; i < 4; i++)
        #pragma unroll
        for (int j = 0; j < 4; j++) acc[i][j] = (floatx4){0.f, 0.f, 0.f, 0.f};

    const unsigned short* Ag = Abf + (size_t)(blockM + srow) * Hn + scol;
    const unsigned short* Bg = Bbf + (size_t)(blockN + srow) * Hn + scol;
    unsigned short* la = &lds_a[(wq * 32) * BK];
    unsigned short* lb = &lds_b[(wq * 32) * BK];

    for (int k0 = 0; k0 < Hn; k0 += BK) {
        #pragma unroll
        for (int it = 0; it < 4; it++) {
            load_lds16(Ag + (size_t)(it * 8) * Hn + k0, la + it * 8 * BK);
            load_lds16(Bg + (size_t)(it * 8) * Hn + k0, lb + it * 8 * BK);
        }
        __syncthreads();   // vmcnt(0) drain => LDS populated
        #pragma unroll
        for (int kk = 0; kk < BK; kk += 32) {
            short8 afr[4], bfr[4];
            #pragma unroll
            for (int j = 0; j < 4; j++)
                bfr[j] = *(const short8*)&lds_b[(wave_n*64 + j*16 + lrow)*BK + kk + quad*8];
            #pragma unroll
            for (int i = 0; i < 4; i++)
                afr[i] = *(const short8*)&lds_a[(wave_m*64 + i*16 + lrow)*BK + kk + quad*8];
            #pragma unroll
            for (int i = 0; i < 4; i++)
                #pragma unroll
                for (int j = 0; j < 4; j++)
                    acc[i][j] = __builtin_amdgcn_mfma_f32_16x16x32_bf16(afr[i], bfr[j], acc[i][j], 0, 0, 0);
        }
        __syncthreads();
    }

    // Epilogue. C/D layout: col=lane&15, row=quad*4+reg (m89-verified).
    float colsum[4] = {0.f, 0.f, 0.f, 0.f};
    #pragma unroll
    for (int j = 0; j < 4; j++) {
        const int c = blockN + wave_n * 64 + j * 16 + lrow;
        const float bbv = bbias[c];
        #pragma unroll
        for (int i = 0; i < 4; i++) {
            const int rbase = blockM + wave_m * 64 + i * 16 + quad * 4;
            #pragma unroll
            for (int reg = 0; reg < 4; reg++) {
                const int r = rbase + reg;
                const size_t idx = (size_t)r * En + c;
                const float t = wv[r] * fast_tanh(acc[i][j][reg] + bbv) * embed[idx];
                outp[idx] = t;
                colsum[j] += t;
            }
        }
    }
    // reduce col sums over the 4 quads (rows) of the wave
    #pragma unroll
    for (int j = 0; j < 4; j++) {
        colsum[j] += __shfl_xor(colsum[j], 16, 64);
        colsum[j] += __shfl_xor(colsum[j], 32, 64);
    }
    __syncthreads();
    float* lds_f = (float*)lds_a;      // reuse LDS after barrier
    if (lane < 16) {
        #pragma unroll
        for (int j = 0; j < 4; j++) lds_f[wq * 64 + j * 16 + lane] = colsum[j];
    }
    __syncthreads();
    if (tid < 128) {
        const int wn = tid >> 6, lc = tid & 63;
        const float s = lds_f[wn * 64 + lc] + lds_f[(wn + 2) * 64 + lc];
        const int b = blockM >> 11;               // /Sn
        const int chunk = (blockM >> 7) & (NCH - 1);
        partial[((size_t)(b * NCH + chunk)) * En + blockN + tid] = s;
    }
}

// ---------------------------------------------------------------------------
// K4: per (b, chunk, 256-e-slab): offset = sum of prior chunk sums, then
//     sequential 128-step cumsum / (cw+eps), in-place in d_out. 1024 blocks.
// ---------------------------------------------------------------------------
__global__ __launch_bounds__(256) void k_cumdiv2(float* __restrict__ t,
                                                 const float* __restrict__ partial,
                                                 const float* __restrict__ cw) {
    const int eb = blockIdx.x & 1;
    const int bc = blockIdx.x >> 1;
    const int b = bc >> 4;            // /NCH
    const int chunk = bc & (NCH - 1);
    const int e = eb * 256 + threadIdx.x;
    float acc = 0.f;
    for (int c = 0; c < chunk; c++) acc += partial[((size_t)(b * NCH + c)) * En + e];
    const int s0 = chunk * CH;
    const float* cwp = cw + (size_t)b * Sn + s0;
    float* p = t + ((size_t)b * Sn + s0) * En + e;
    for (int s = 0; s < CH; s += 8) {
        float v[8], d[8];
        #pragma unroll
        for (int j = 0; j < 8; j++) v[j] = p[(size_t)(s + j) * En];
        #pragma unroll
        for (int j = 0; j < 8; j++) d[j] = cwp[s + j];
        #pragma unroll
        for (int j = 0; j < 8; j++) {
            acc += v[j];
            p[(size_t)(s + j) * En] = acc / (d[j] + 1e-10f);
        }
    }
}

extern "C" void kernel_launch(void* const* d_in, const int* in_sizes, int n_in,
                              void* d_out, int out_size, void* d_ws, size_t ws_size,
                              hipStream_t stream) {
    const float* alpha = (const float*)d_in[0];
    const float* beta  = (const float*)d_in[1];
    const float* embed = (const float*)d_in[2];
    const float* Wb    = (const float*)d_in[3];
    const float* bb    = (const float*)d_in[4];
    const float* Wa    = (const float*)d_in[5];
    const float* ba    = (const float*)d_in[6];
    float* out = (float*)d_out;

    // workspace layout (~66 MB)
    unsigned short* beta_bf = (unsigned short*)d_ws;           // Mn*Hn bf16 (64 MB)
    unsigned short* wb_bf   = beta_bf + (size_t)Mn * Hn;       // En*Hn bf16 (0.5 MB)
    float* wbuf    = (float*)(wb_bf + (size_t)En * Hn);        // Mn
    float* cwbuf   = wbuf + Mn;                                // Mn
    float* partial = cwbuf + Mn;                               // Bn*NCH*En (1 MB)

    k_conv<<<(Mn * Hn / 8 + 255) / 256, 256, 0, stream>>>(beta, beta_bf, Mn * Hn / 8);
    k_conv<<<(En * Hn / 8 + 255) / 256, 256, 0, stream>>>(Wb, wb_bf, En * Hn / 8);
    k_w<<<Mn / 4, 256, 0, stream>>>(alpha, Wa, ba, wbuf);
    k_scan_w<<<Bn, 64, 0, stream>>>(wbuf, cwbuf);
    dim3 g3(En / 128, Mn / 128);
    k_gemm2<<<g3, 256, 0, stream>>>(beta_bf, wb_bf, bb, wbuf, embed, out, partial);
    k_cumdiv2<<<Bn * NCH * 2, 256, 0, stream>>>(out, partial, cwbuf);
}